// Round 9
// baseline (690.739 us; speedup 1.0000x reference)
//
#include <hip/hip_runtime.h>
#include <hip/hip_bf16.h>
#include <stdint.h>

using bf16 = __hip_bfloat16;
typedef __attribute__((ext_vector_type(8))) short short8;
typedef __attribute__((ext_vector_type(4))) float f32x4;

#define LRELU_SLOPE 0.01f

// async global->LDS, 16B/lane; LDS dest = wave-uniform base + lane*16
#define GLOAD_LDS16(g, l) __builtin_amdgcn_global_load_lds( \
    (const __attribute__((address_space(1))) void*)(g),     \
    (__attribute__((address_space(3))) void*)(l), 16, 0, 0)

__device__ __forceinline__ float b2f(short s) {
    union { uint32_t u; float f; } cv;
    cv.u = ((uint32_t)(uint16_t)s) << 16;
    return cv.f;
}
__device__ __forceinline__ short f2b(float f) {
    bf16 h = __float2bfloat16(f);
    return *reinterpret_cast<short*>(&h);
}

// ---------------------------------------------------------------------------
// Generic GEMM, M-tile 64, Dout=128, full-K LDS staging (no per-BK barriers).
// Used for embed (K=64) and s (K=128). Block 256 = 4 waves, wave 32x64.
// Epilogue: acc -> LDS (reusing As) -> vectorized 16B full-line stores.
// ---------------------------------------------------------------------------
__global__ __launch_bounds__(256) void gemm_m64_kernel(
    const bf16* __restrict__ A, int lda,
    const bf16* __restrict__ BT,
    const float* __restrict__ bias,
    bf16* __restrict__ C, int ldc,
    int N, int K, int cprShift, int act)
{
    __shared__ bf16 As[64 * 128];          // 16 KB (K<=128; also epilogue buf)
    const int t   = threadIdx.x;
    const int wv  = t >> 6, ln = t & 63, m16 = ln & 15, q = ln >> 4;
    const int row0 = blockIdx.x * 64;
    const int col0 = (wv >> 1) * 64;
    const int wr   = (wv & 1) * 32;
    const int cmask = (1 << cprShift) - 1;
    const int trips = (1 << cprShift) >> 2;

    for (int i = 0; i < trips; ++i) {
        int g    = i * 256 + t;
        int row  = g >> cprShift;
        int cidx = (g & cmask) ^ (row & cmask);
        int grow = row0 + row; if (grow > N - 1) grow = N - 1;
        GLOAD_LDS16(A + (size_t)grow * lda + cidx * 8,
                    As + ((i * 256 + wv * 64) << 3));
    }
    __syncthreads();

    f32x4 acc[2][4];
#pragma unroll
    for (int mi = 0; mi < 2; ++mi)
#pragma unroll
        for (int ni = 0; ni < 4; ++ni)
            acc[mi][ni] = (f32x4){0.f, 0.f, 0.f, 0.f};

    for (int k0 = 0; k0 < K; k0 += 32) {
        int cbase = (k0 >> 3) + q;
        short8 a[2], b[4];
#pragma unroll
        for (int mi = 0; mi < 2; ++mi) {
            int row = wr + mi * 16 + m16;
            int cs  = cbase ^ (row & cmask);
            a[mi] = *reinterpret_cast<const short8*>(As + row * K + cs * 8);
        }
#pragma unroll
        for (int ni = 0; ni < 4; ++ni)
            b[ni] = *reinterpret_cast<const short8*>(
                BT + (size_t)(col0 + ni * 16 + m16) * K + k0 + q * 8);
#pragma unroll
        for (int mi = 0; mi < 2; ++mi)
#pragma unroll
            for (int ni = 0; ni < 4; ++ni)
                acc[mi][ni] = __builtin_amdgcn_mfma_f32_16x16x32_bf16(
                    a[mi], b[ni], acc[mi][ni], 0, 0, 0);
    }
    __syncthreads();   // all k-loop As reads done before epilogue overwrite

    // epilogue: acc -> As[64][128] (swizzled), then 16B stores
#pragma unroll
    for (int mi = 0; mi < 2; ++mi) {
#pragma unroll
        for (int ni = 0; ni < 4; ++ni) {
            int col = col0 + ni * 16 + m16;
            float bv = bias[col];
#pragma unroll
            for (int r = 0; r < 4; ++r) {
                int lrow = wr + mi * 16 + q * 4 + r;
                float v = acc[mi][ni][r] + bv;
                if (act) v = (v > 0.f) ? v : LRELU_SLOPE * v;
                short sv = f2b(v);
                As[lrow * 128 + (((col >> 3) ^ (lrow & 15)) << 3) + (col & 7)] =
                    *reinterpret_cast<bf16*>(&sv);
            }
        }
    }
    __syncthreads();
#pragma unroll
    for (int i = 0; i < 4; ++i) {
        int s   = i * 256 + t;
        int row = s >> 4, c = s & 15;
        int grow = row0 + row;
        if (grow < N) {
            short8 v = *reinterpret_cast<const short8*>(
                As + row * 128 + ((c ^ (row & 15)) << 3));
            *reinterpret_cast<short8*>(C + (size_t)grow * ldc + c * 8) = v;
        }
    }
}

// ---------------------------------------------------------------------------
// Fused layer kernel v5b: m-GEMM + gates-GEMM + GRU for 64 rows.
// Block = 512 thr = 8 waves: rh = wv&1 (row half, 32 rows), cq = wv>>1
// (col quarter). LDS 48 KB, three [64][128] bf16 regions:
//   R0 = agg (later m_lo, later h_out) | R1 = h | R2 = m_hi.
// All regions: 16B chunk c of row r at c ^ (r & 15) (measured 0 conflicts).
// Phase 1 (m): wave = 32 rows x 64 m-cols (acc 32 VGPR).
// Phase 2 (gates): wave = 32 rows x 32 ch x 4 gates (acc 64 VGPR)
//   [v5 BUG FIX: was 16 ch -> channels 64..127 never computed].
// GRU register-local; h_prev from R1; epilogue via R0 -> 16B stores.
// ---------------------------------------------------------------------------
__global__ __launch_bounds__(512) void layer_kernel(
    const bf16* __restrict__ cat,    // [N64][256] = [agg | h]
    const bf16* __restrict__ WM,     // [256][256] W_rec^T
    const float* __restrict__ bM,    // [256]
    const bf16* __restrict__ WX,     // [512][384] W_ext^T (r|z|inn|hn)
    const float* __restrict__ bX,    // [512]
    bf16* __restrict__ catH,         // cat + 128 (ld 256); skipped when last
    float* __restrict__ out32,       // d_out (ld 128); written iff last
    int N, int last)
{
    __shared__ bf16 smem[24576];     // 48 KB
    bf16* R0 = smem;                 // agg -> m_lo -> h_out
    bf16* R1 = smem + 8192;          // h
    bf16* R2 = smem + 16384;         // m_hi

    const int t  = threadIdx.x;
    const int wv = t >> 6, ln = t & 63, m16 = ln & 15, q = ln >> 4;
    const int rh = wv & 1;           // row half (32 rows)
    const int cq = wv >> 1;          // col quarter
    const int row0 = blockIdx.x * 64;

    // ---- stage agg + h: 2048 chunks of 16B, 4 trips ----
#pragma unroll
    for (int i = 0; i < 4; ++i) {
        int s    = i * 512 + t;
        int R    = s >> 10;              // 0=agg, 1=h
        int row  = (s >> 4) & 63;
        int c    = (s & 15) ^ (row & 15);
        int grow = row0 + row; if (grow > N - 1) grow = N - 1;
        GLOAD_LDS16(cat + (size_t)grow * 256 + R * 128 + c * 8,
                    smem + ((i * 512 + wv * 64) << 3));
    }
    __syncthreads();

    // ---- phase 1: m = lrelu([agg|h] @ WM + bM); wave = 32 rows x 64 cols ----
    f32x4 macc[2][4];
#pragma unroll
    for (int mi = 0; mi < 2; ++mi)
#pragma unroll
        for (int ni = 0; ni < 4; ++ni)
            macc[mi][ni] = (f32x4){0.f, 0.f, 0.f, 0.f};

#pragma unroll
    for (int k0 = 0; k0 < 256; k0 += 32) {
        const bf16* Rg = (k0 < 128) ? R0 : R1;
        int kl = k0 & 127;
        short8 a[2], b[4];
#pragma unroll
        for (int mi = 0; mi < 2; ++mi) {
            int row = rh * 32 + mi * 16 + m16;
            int c   = ((kl >> 3) + q) ^ m16;
            a[mi] = *reinterpret_cast<const short8*>(Rg + row * 128 + c * 8);
        }
#pragma unroll
        for (int ni = 0; ni < 4; ++ni)
            b[ni] = *reinterpret_cast<const short8*>(
                WM + (size_t)(cq * 64 + ni * 16 + m16) * 256 + k0 + q * 8);
#pragma unroll
        for (int mi = 0; mi < 2; ++mi)
#pragma unroll
            for (int ni = 0; ni < 4; ++ni)
                macc[mi][ni] = __builtin_amdgcn_mfma_f32_16x16x32_bf16(
                    a[mi], b[ni], macc[mi][ni], 0, 0, 0);
    }
    __syncthreads();   // agg reads done before m_lo overwrites R0

    // ---- write m (bf16) into R0 (ch<128) / R2 (ch>=128) ----
#pragma unroll
    for (int mi = 0; mi < 2; ++mi) {
#pragma unroll
        for (int ni = 0; ni < 4; ++ni) {
            int ch  = cq * 64 + ni * 16 + m16;
            bf16* MR = (ch < 128) ? R0 : R2;
            int chl = ch & 127;
            float bv = bM[ch];
#pragma unroll
            for (int r = 0; r < 4; ++r) {
                int row = rh * 32 + mi * 16 + q * 4 + r;
                float v = macc[mi][ni][r] + bv;
                v = (v > 0.f) ? v : LRELU_SLOPE * v;
                short sv = f2b(v);
                MR[row * 128 + (((chl >> 3) ^ (row & 15)) << 3) + (chl & 7)] =
                    *reinterpret_cast<bf16*>(&sv);
            }
        }
    }
    __syncthreads();

    // ---- phase 2: gates; wave = 32 rows x 32 ch x 4 gates ----
    f32x4 gr[2][2], gz[2][2], gn_[2][2], gh_[2][2];
#pragma unroll
    for (int mi = 0; mi < 2; ++mi)
#pragma unroll
        for (int ni = 0; ni < 2; ++ni) {
            gr[mi][ni]  = (f32x4){0.f, 0.f, 0.f, 0.f};
            gz[mi][ni]  = (f32x4){0.f, 0.f, 0.f, 0.f};
            gn_[mi][ni] = (f32x4){0.f, 0.f, 0.f, 0.f};
            gh_[mi][ni] = (f32x4){0.f, 0.f, 0.f, 0.f};
        }

    // k in [0,256): A = m (R0/R2); gates r, z, inn
#pragma unroll
    for (int k0 = 0; k0 < 256; k0 += 32) {
        const bf16* Rg = (k0 < 128) ? R0 : R2;
        int kl = k0 & 127;
        short8 a[2];
#pragma unroll
        for (int mi = 0; mi < 2; ++mi) {
            int row = rh * 32 + mi * 16 + m16;
            int c   = ((kl >> 3) + q) ^ m16;
            a[mi] = *reinterpret_cast<const short8*>(Rg + row * 128 + c * 8);
        }
        short8 br[2], bz[2], bn[2];
#pragma unroll
        for (int ni = 0; ni < 2; ++ni) {
            int cw = cq * 32 + ni * 16 + m16;
            br[ni] = *reinterpret_cast<const short8*>(WX + (size_t)(cw)       * 384 + k0 + q * 8);
            bz[ni] = *reinterpret_cast<const short8*>(WX + (size_t)(128 + cw) * 384 + k0 + q * 8);
            bn[ni] = *reinterpret_cast<const short8*>(WX + (size_t)(256 + cw) * 384 + k0 + q * 8);
        }
#pragma unroll
        for (int mi = 0; mi < 2; ++mi)
#pragma unroll
            for (int ni = 0; ni < 2; ++ni) {
                gr[mi][ni]  = __builtin_amdgcn_mfma_f32_16x16x32_bf16(a[mi], br[ni], gr[mi][ni], 0, 0, 0);
                gz[mi][ni]  = __builtin_amdgcn_mfma_f32_16x16x32_bf16(a[mi], bz[ni], gz[mi][ni], 0, 0, 0);
                gn_[mi][ni] = __builtin_amdgcn_mfma_f32_16x16x32_bf16(a[mi], bn[ni], gn_[mi][ni], 0, 0, 0);
            }
    }
    // k in [256,384): A = h (R1); gates r, z, hn
#pragma unroll
    for (int k0 = 256; k0 < 384; k0 += 32) {
        int kl = k0 - 256;
        short8 a[2];
#pragma unroll
        for (int mi = 0; mi < 2; ++mi) {
            int row = rh * 32 + mi * 16 + m16;
            int c   = ((kl >> 3) + q) ^ m16;
            a[mi] = *reinterpret_cast<const short8*>(R1 + row * 128 + c * 8);
        }
        short8 br[2], bz[2], bh[2];
#pragma unroll
        for (int ni = 0; ni < 2; ++ni) {
            int cw = cq * 32 + ni * 16 + m16;
            br[ni] = *reinterpret_cast<const short8*>(WX + (size_t)(cw)       * 384 + k0 + q * 8);
            bz[ni] = *reinterpret_cast<const short8*>(WX + (size_t)(128 + cw) * 384 + k0 + q * 8);
            bh[ni] = *reinterpret_cast<const short8*>(WX + (size_t)(384 + cw) * 384 + k0 + q * 8);
        }
#pragma unroll
        for (int mi = 0; mi < 2; ++mi)
#pragma unroll
            for (int ni = 0; ni < 2; ++ni) {
                gr[mi][ni]  = __builtin_amdgcn_mfma_f32_16x16x32_bf16(a[mi], br[ni], gr[mi][ni], 0, 0, 0);
                gz[mi][ni]  = __builtin_amdgcn_mfma_f32_16x16x32_bf16(a[mi], bz[ni], gz[mi][ni], 0, 0, 0);
                gh_[mi][ni] = __builtin_amdgcn_mfma_f32_16x16x32_bf16(a[mi], bh[ni], gh_[mi][ni], 0, 0, 0);
            }
    }
    __syncthreads();   // R0 (m_lo) reads done before h_out overwrites

    // ---- GRU: register-local; h_prev from R1; h_new -> R0 ----
#pragma unroll
    for (int mi = 0; mi < 2; ++mi) {
#pragma unroll
        for (int ni = 0; ni < 2; ++ni) {
            int ch = cq * 32 + ni * 16 + m16;     // h-channel 0..127
            float brv = bX[ch], bzv = bX[128 + ch];
            float bnv = bX[256 + ch], bhv = bX[384 + ch];
#pragma unroll
            for (int r = 0; r < 4; ++r) {
                int lrow = rh * 32 + mi * 16 + q * 4 + r;
                int c = ((ch >> 3) ^ (lrow & 15)) << 3;
                float hv = b2f(*reinterpret_cast<const short*>(
                    R1 + lrow * 128 + c + (ch & 7)));
                float rr = 1.f / (1.f + __expf(-(gr[mi][ni][r] + brv)));
                float zz = 1.f / (1.f + __expf(-(gz[mi][ni][r] + bzv)));
                float nn = tanhf(gn_[mi][ni][r] + bnv + rr * (gh_[mi][ni][r] + bhv));
                float hnew = (1.f - zz) * nn + zz * hv;
                short hb = f2b(hnew);
                R0[lrow * 128 + c + (ch & 7)] = *reinterpret_cast<bf16*>(&hb);
            }
        }
    }
    __syncthreads();

    // ---- copy-out: 16B full-line stores, 2 trips ----
#pragma unroll
    for (int i = 0; i < 2; ++i) {
        int s   = i * 512 + t;
        int row = s >> 4, c = s & 15;
        int grow = row0 + row;
        if (grow < N) {
            short8 v = *reinterpret_cast<const short8*>(
                R0 + row * 128 + ((c ^ (row & 15)) << 3));
            if (last) {
                f32x4 lo, hi;
#pragma unroll
                for (int j = 0; j < 4; ++j) { lo[j] = b2f(v[j]); hi[j] = b2f(v[j + 4]); }
                float* dst = out32 + (size_t)grow * 128 + c * 8;
                *reinterpret_cast<f32x4*>(dst)     = lo;
                *reinterpret_cast<f32x4*>(dst + 4) = hi;
            } else {
                *reinterpret_cast<short8*>(catH + (size_t)grow * 256 + c * 8) = v;
            }
        }
    }
}

// ---------------------------------------------------------------------------
// prep: x->bf16, weight transposes, W_ext (512x384, zero-padded), b_ext
// ---------------------------------------------------------------------------
__global__ void prep_kernel(const float* __restrict__ x, bf16* __restrict__ xb, int nx,
                            const float* __restrict__ W_embed, bf16* __restrict__ TE,
                            const float* __restrict__ W_snd,   bf16* __restrict__ TS,
                            const float* __restrict__ W_rec,   bf16* __restrict__ TM,
                            const float* __restrict__ W_ih, const float* __restrict__ W_hh,
                            bf16* __restrict__ TX,
                            const float* __restrict__ b_ih, const float* __restrict__ b_hh,
                            float* __restrict__ bext)
{
    int t = blockIdx.x * 256 + threadIdx.x;
    if (t < nx) { xb[t] = __float2bfloat16(x[t]); return; }
    t -= nx;
    if (t < 8192)  { TE[(t % 128) * 64  + t / 128] = __float2bfloat16(W_embed[t]); return; }
    t -= 8192;
    if (t < 16384) { TS[(t % 128) * 128 + t / 128] = __float2bfloat16(W_snd[t]); return; }
    t -= 16384;
    if (t < 65536) { TM[(t % 256) * 256 + t / 256] = __float2bfloat16(W_rec[t]); return; }
    t -= 65536;
    if (t < 196608) {
        int c = t / 384, k = t - c * 384;
        float v;
        if (c < 256)      v = (k < 256) ? W_ih[k * 384 + c] : W_hh[(k - 256) * 384 + c];
        else if (c < 384) v = (k < 256) ? W_ih[k * 384 + c] : 0.f;
        else              v = (k < 256) ? 0.f : W_hh[(k - 256) * 384 + (c - 128)];
        TX[t] = __float2bfloat16(v);
        return;
    }
    t -= 196608;
    if (t < 512) {
        float v;
        if (t < 256)      v = b_ih[t] + b_hh[t];
        else if (t < 384) v = b_ih[t];
        else              v = b_hh[t - 128];
        bext[t] = v;
    }
}

// ---------------------------------------------------------------------------
// CSR build
// ---------------------------------------------------------------------------
__global__ void hist_kernel(const int* __restrict__ col, int* __restrict__ cnt, int E)
{
    int e = blockIdx.x * 256 + threadIdx.x;
    if (e < E) atomicAdd(&cnt[col[e]], 1);
}

__global__ void blockscan_kernel(const int* __restrict__ cnt, int* __restrict__ off,
                                 int* __restrict__ bsum, int N)
{
    __shared__ int sm[256];
    int i = blockIdx.x * 256 + threadIdx.x;
    int v = (i < N) ? cnt[i] : 0;
    sm[threadIdx.x] = v;
    __syncthreads();
    for (int d = 1; d < 256; d <<= 1) {
        int tv = (threadIdx.x >= (unsigned)d) ? sm[threadIdx.x - d] : 0;
        __syncthreads();
        sm[threadIdx.x] += tv;
        __syncthreads();
    }
    if (i < N) off[i] = sm[threadIdx.x] - v;
    if (threadIdx.x == 255) bsum[blockIdx.x] = sm[255];
}

__global__ void bscan_kernel(int* __restrict__ bsum, int nb)
{
    __shared__ int sm[512];
    int v = (threadIdx.x < (unsigned)nb) ? bsum[threadIdx.x] : 0;
    sm[threadIdx.x] = v;
    __syncthreads();
    for (int d = 1; d < 512; d <<= 1) {
        int tv = (threadIdx.x >= (unsigned)d) ? sm[threadIdx.x - d] : 0;
        __syncthreads();
        sm[threadIdx.x] += tv;
        __syncthreads();
    }
    if (threadIdx.x < (unsigned)nb) bsum[threadIdx.x] = sm[threadIdx.x] - v;
}

__global__ void addoff_kernel(int* __restrict__ off, const int* __restrict__ bsum,
                              const int* __restrict__ cnt, float* __restrict__ icnt,
                              int N, int E)
{
    int i = blockIdx.x * 256 + threadIdx.x;
    if (i < N) {
        off[i] += bsum[blockIdx.x];
        icnt[i] = 1.0f / fmaxf((float)cnt[i], 1.0f);
    }
    if (i == 0) off[N] = E;
}

// packed (row, weight) 8B scatter
__global__ void fill_kernel(const int* __restrict__ row, const int* __restrict__ col,
                            const float* __restrict__ ea, const int* __restrict__ off,
                            int* __restrict__ fil, int2* __restrict__ re, int E)
{
    int e = blockIdx.x * 256 + threadIdx.x;
    if (e < E) {
        int c = col[e];
        int p = atomicAdd(&fil[c], 1);
        int2 v; v.x = row[e]; v.y = __float_as_int(ea[e]);
        re[off[c] + p] = v;
    }
}

// ---------------------------------------------------------------------------
// aggregation: wave per node; 4x16-lane groups, one edge per group per trip,
// unrolled x2 (8 gathers in flight per wave)
// ---------------------------------------------------------------------------
__global__ void agg_kernel(const int* __restrict__ off,
                           const int2* __restrict__ re,
                           const bf16* __restrict__ s,
                           const float* __restrict__ icnt,
                           bf16* __restrict__ cat, int N)
{
    int wid  = (int)((blockIdx.x * blockDim.x + threadIdx.x) >> 6);
    int lane = threadIdx.x & 63;
    if (wid >= N) return;
    const int rg = lane >> 4;
    const int cl = lane & 15;
    int b = off[wid], e = off[wid + 1];

    float acc[8];
#pragma unroll
    for (int j = 0; j < 8; ++j) acc[j] = 0.f;

    int i = b + rg;
    for (; i + 4 < e; i += 8) {
        int2 p0 = re[i];
        int2 p1 = re[i + 4];
        short8 v0 = *reinterpret_cast<const short8*>(s + (size_t)p0.x * 128 + cl * 8);
        short8 v1 = *reinterpret_cast<const short8*>(s + (size_t)p1.x * 128 + cl * 8);
        float w0 = __int_as_float(p0.y), w1 = __int_as_float(p1.y);
#pragma unroll
        for (int j = 0; j < 8; ++j) acc[j] += w0 * b2f(v0[j]) + w1 * b2f(v1[j]);
    }
    if (i < e) {
        int2 p0 = re[i];
        float w0 = __int_as_float(p0.y);
        short8 v0 = *reinterpret_cast<const short8*>(s + (size_t)p0.x * 128 + cl * 8);
#pragma unroll
        for (int j = 0; j < 8; ++j) acc[j] += w0 * b2f(v0[j]);
    }
#pragma unroll
    for (int j = 0; j < 8; ++j) {
        acc[j] += __shfl_xor(acc[j], 16, 64);
        acc[j] += __shfl_xor(acc[j], 32, 64);
    }
    if (rg == 0) {
        float ic = icnt[wid];
        short8 o;
#pragma unroll
        for (int j = 0; j < 8; ++j) o[j] = f2b(acc[j] * ic);
        *reinterpret_cast<short8*>(cat + (size_t)wid * 256 + cl * 8) = o;
    }
}

// ---------------------------------------------------------------------------
extern "C" void kernel_launch(void* const* d_in, const int* in_sizes, int n_in,
                              void* d_out, int out_size, void* d_ws, size_t ws_size,
                              hipStream_t stream)
{
    const float* x       = (const float*)d_in[0];
    const int*   ei      = (const int*)d_in[1];
    const float* ea      = (const float*)d_in[2];
    const float* W_embed = (const float*)d_in[4];
    const float* b_embed = (const float*)d_in[5];
    const float* W_snd   = (const float*)d_in[6];
    const float* b_snd   = (const float*)d_in[7];
    const float* W_rec   = (const float*)d_in[8];
    const float* b_rec   = (const float*)d_in[9];
    const float* W_ih    = (const float*)d_in[10];
    const float* b_ih    = (const float*)d_in[11];
    const float* W_hh    = (const float*)d_in[12];
    const float* b_hh    = (const float*)d_in[13];

    const int N = in_sizes[3];
    const int E = in_sizes[2];
    const int N64 = ((N + 63) / 64) * 64;

    char* p = (char*)d_ws;
    auto carve = [&](size_t bytes) {
        char* r = p;
        p += (bytes + 255) & ~(size_t)255;
        return (void*)r;
    };
    bf16*  xb   = (bf16*) carve((size_t)N64 * 64  * 2);
    bf16*  cat  = (bf16*) carve((size_t)N64 * 256 * 2);   // [agg | h]
    bf16*  sbuf = (bf16*) carve((size_t)N64 * 128 * 2);
    int2*  re   = (int2*) carve((size_t)E * 8);
    int*   cnt  = (int*)  carve((size_t)N * 4);
    int*   fil  = (int*)  carve((size_t)N * 4);
    int*   off  = (int*)  carve((size_t)(N + 1) * 4);
    int*   bsum = (int*)  carve((size_t)512 * 4);
    float* icnt = (float*)carve((size_t)N * 4);
    bf16*  wtE  = (bf16*) carve((size_t)128 * 64 * 2);
    bf16*  wtS  = (bf16*) carve((size_t)128 * 128 * 2);
    bf16*  wtM  = (bf16*) carve((size_t)256 * 256 * 2);
    bf16*  wtX  = (bf16*) carve((size_t)512 * 384 * 2);
    float* bext = (float*)carve((size_t)512 * 4);

    const int* rowp = ei;
    const int* colp = ei + E;

    hipMemsetAsync(cnt, 0, (size_t)N * 4, stream);
    hipMemsetAsync(fil, 0, (size_t)N * 4, stream);

    const int TB = 256;
    auto nb = [](int n) { return (n + 255) / 256; };

    prep_kernel<<<nb(N * 64 + 287232), TB, 0, stream>>>(
        x, xb, N * 64, W_embed, wtE, W_snd, wtS, W_rec, wtM,
        W_ih, W_hh, wtX, b_ih, b_hh, bext);

    hist_kernel<<<nb(E), TB, 0, stream>>>(colp, cnt, E);
    blockscan_kernel<<<nb(N), TB, 0, stream>>>(cnt, off, bsum, N);
    bscan_kernel<<<1, 512, 0, stream>>>(bsum, nb(N));
    addoff_kernel<<<nb(N), TB, 0, stream>>>(off, bsum, cnt, icnt, N, E);
    fill_kernel<<<nb(E), TB, 0, stream>>>(rowp, colp, ea, off, fil, re, E);

    const int gx = (N + 63) / 64;

    // embed: h = x @ W_embed + b -> cat[:,128:256] (bf16)
    gemm_m64_kernel<<<gx, TB, 0, stream>>>(xb, 64, wtE, b_embed,
                                           cat + 128, 256, N, 64, 3, 0);

    for (int L = 0; L < 3; ++L) {
        // s = lrelu(h @ W_snd + b_snd)
        gemm_m64_kernel<<<gx, TB, 0, stream>>>(cat + 128, 256, wtS, b_snd,
                                               sbuf, 128, N, 128, 4, 1);
        // agg = segment_mean(s[row] * ea) -> cat[:,0:128]
        agg_kernel<<<(N * 64 + TB - 1) / TB, TB, 0, stream>>>(off, re, sbuf,
                                                              icnt, cat, N);
        // fused m + gates + GRU -> cat[:,128:256] (or d_out fp32 when last)
        layer_kernel<<<gx, 512, 0, stream>>>(cat, wtM, b_rec, wtX, bext,
                                             cat + 128, (float*)d_out,
                                             N, (L == 2) ? 1 : 0);
    }
}

// Round 10
// 583.908 us; speedup vs baseline: 1.1830x; 1.1830x over previous
//
#include <hip/hip_runtime.h>
#include <hip/hip_bf16.h>
#include <stdint.h>

using bf16 = __hip_bfloat16;
typedef __attribute__((ext_vector_type(8))) short short8;
typedef __attribute__((ext_vector_type(4))) float f32x4;

#define LRELU_SLOPE 0.01f

// async global->LDS, 16B/lane; LDS dest = wave-uniform base + lane*16
#define GLOAD_LDS16(g, l) __builtin_amdgcn_global_load_lds( \
    (const __attribute__((address_space(1))) void*)(g),     \
    (__attribute__((address_space(3))) void*)(l), 16, 0, 0)

#define MFMA16(a, b, c) __builtin_amdgcn_mfma_f32_16x16x32_bf16((a), (b), (c), 0, 0, 0)

__device__ __forceinline__ float b2f(short s) {
    union { uint32_t u; float f; } cv;
    cv.u = ((uint32_t)(uint16_t)s) << 16;
    return cv.f;
}
__device__ __forceinline__ short f2b(float f) {
    bf16 h = __float2bfloat16(f);
    return *reinterpret_cast<short*>(&h);
}

// ---------------------------------------------------------------------------
// Embed kernel: h = x @ WE + bE -> catH; s = lrelu(h @ WS + bS) -> sbuf.
// Block 256 = 4 waves. LDS 32 KB: H[64][128] bounce + X (x staging, later s
// bounce). h-GEMM: wave 32 rows x 64 cols; s-GEMM: wave 64 rows x 32 cols.
// Swizzles: x staging chunk c of row r at c^(r&7); H/X 128-wide regions use
// chunk c of row r at c^(r&15) (measured 0 conflicts).
// ---------------------------------------------------------------------------
__global__ __launch_bounds__(256) void embed_kernel(
    const bf16* __restrict__ xb,     // [N64][64]
    const bf16* __restrict__ WE,     // [128][64]  W_embed^T
    const float* __restrict__ bE,
    const bf16* __restrict__ WS,     // [128][128] W_snd^T
    const float* __restrict__ bS,
    bf16* __restrict__ catH,         // cat + 128 (ld 256)
    bf16* __restrict__ sbuf,         // [N64][128]
    int N)
{
    __shared__ bf16 H[8192];         // 16 KB: h bounce
    __shared__ bf16 X[8192];         // 16 KB: x staging (8 KB used) -> s bounce
    const int t   = threadIdx.x;
    const int wv  = t >> 6, ln = t & 63, m16 = ln & 15, q = ln >> 4;
    const int row0 = blockIdx.x * 64;

    // stage x: 512 chunks of 16B, 2 trips
#pragma unroll
    for (int i = 0; i < 2; ++i) {
        int g    = i * 256 + t;
        int row  = g >> 3;
        int cidx = (g & 7) ^ (row & 7);
        int grow = row0 + row; if (grow > N - 1) grow = N - 1;
        GLOAD_LDS16(xb + (size_t)grow * 64 + cidx * 8,
                    X + ((i * 256 + wv * 64) << 3));
    }
    __syncthreads();

    // h-GEMM: wave (wv&1)=row-half, (wv>>1)=col-half; K=64
    const int col0 = (wv >> 1) * 64;
    const int wr   = (wv & 1) * 32;
    f32x4 acc[2][4];
#pragma unroll
    for (int mi = 0; mi < 2; ++mi)
#pragma unroll
        for (int ni = 0; ni < 4; ++ni)
            acc[mi][ni] = (f32x4){0.f, 0.f, 0.f, 0.f};

#pragma unroll
    for (int k0 = 0; k0 < 64; k0 += 32) {
        short8 a[2], b[4];
#pragma unroll
        for (int mi = 0; mi < 2; ++mi) {
            int row = wr + mi * 16 + m16;
            int cs  = ((k0 >> 3) + q) ^ (row & 7);
            a[mi] = *reinterpret_cast<const short8*>(X + row * 64 + cs * 8);
        }
#pragma unroll
        for (int ni = 0; ni < 4; ++ni)
            b[ni] = *reinterpret_cast<const short8*>(
                WE + (size_t)(col0 + ni * 16 + m16) * 64 + k0 + q * 8);
#pragma unroll
        for (int mi = 0; mi < 2; ++mi)
#pragma unroll
            for (int ni = 0; ni < 4; ++ni)
                acc[mi][ni] = MFMA16(a[mi], b[ni], acc[mi][ni]);
    }

    // h epilogue -> H (swizzled)
#pragma unroll
    for (int mi = 0; mi < 2; ++mi) {
#pragma unroll
        for (int ni = 0; ni < 4; ++ni) {
            int col = col0 + ni * 16 + m16;
            float bv = bE[col];
#pragma unroll
            for (int r = 0; r < 4; ++r) {
                int lrow = wr + mi * 16 + q * 4 + r;
                short sv = f2b(acc[mi][ni][r] + bv);
                H[lrow * 128 + (((col >> 3) ^ (lrow & 15)) << 3) + (col & 7)] =
                    *reinterpret_cast<bf16*>(&sv);
            }
        }
    }
    __syncthreads();

    // copy-out h
#pragma unroll
    for (int i = 0; i < 4; ++i) {
        int s   = i * 256 + t;
        int row = s >> 4, c = s & 15;
        int grow = row0 + row;
        if (grow < N) {
            short8 v = *reinterpret_cast<const short8*>(
                H + row * 128 + ((c ^ (row & 15)) << 3));
            *reinterpret_cast<short8*>(catH + (size_t)grow * 256 + c * 8) = v;
        }
    }

    // s-GEMM: wave = 64 rows x 32 cols; K=128 over H
    f32x4 sacc[4][2];
#pragma unroll
    for (int mi = 0; mi < 4; ++mi)
#pragma unroll
        for (int ni = 0; ni < 2; ++ni)
            sacc[mi][ni] = (f32x4){0.f, 0.f, 0.f, 0.f};

#pragma unroll
    for (int k0 = 0; k0 < 128; k0 += 32) {
        short8 a[4], b[2];
#pragma unroll
        for (int mi = 0; mi < 4; ++mi) {
            int row = mi * 16 + m16;
            int c   = ((k0 >> 3) + q) ^ m16;
            a[mi] = *reinterpret_cast<const short8*>(H + row * 128 + c * 8);
        }
#pragma unroll
        for (int ni = 0; ni < 2; ++ni)
            b[ni] = *reinterpret_cast<const short8*>(
                WS + (size_t)(wv * 32 + ni * 16 + m16) * 128 + k0 + q * 8);
#pragma unroll
        for (int mi = 0; mi < 4; ++mi)
#pragma unroll
            for (int ni = 0; ni < 2; ++ni)
                sacc[mi][ni] = MFMA16(a[mi], b[ni], sacc[mi][ni]);
    }

    // s -> X (swizzled)
#pragma unroll
    for (int mi = 0; mi < 4; ++mi) {
#pragma unroll
        for (int ni = 0; ni < 2; ++ni) {
            int ch = wv * 32 + ni * 16 + m16;
            float bv = bS[ch];
#pragma unroll
            for (int r = 0; r < 4; ++r) {
                int row = mi * 16 + q * 4 + r;
                float v = sacc[mi][ni][r] + bv;
                v = (v > 0.f) ? v : LRELU_SLOPE * v;
                short sv = f2b(v);
                X[row * 128 + (((ch >> 3) ^ (row & 15)) << 3) + (ch & 7)] =
                    *reinterpret_cast<bf16*>(&sv);
            }
        }
    }
    __syncthreads();
#pragma unroll
    for (int i = 0; i < 4; ++i) {
        int s   = i * 256 + t;
        int row = s >> 4, c = s & 15;
        int grow = row0 + row;
        if (grow < N) {
            short8 v = *reinterpret_cast<const short8*>(
                X + row * 128 + ((c ^ (row & 15)) << 3));
            *reinterpret_cast<short8*>(sbuf + (size_t)grow * 128 + c * 8) = v;
        }
    }
}

// ---------------------------------------------------------------------------
// Fused layer kernel v6: m-GEMM + gates-GEMM (software-pipelined weight
// loads) + GRU + next-layer s-GEMM, for 64 rows. Block = 256 thr = 4 waves
// (round-7 config: best measured). LDS 48 KB, three [64][128] regions:
//   R0 = agg -> m_lo -> h_out | R1 = h -> s bounce | R2 = m_hi.
// Chunk c of row r at c ^ (r & 15) (measured 0 conflicts).
// Phase 1 (m): wave = 64 rows x 64 m-cols. Phase 2 (gates): wave = 64 rows
// x 32 ch x 4 gates, 2-stage register pipeline on the 6 weight fragments
// (next k-step's loads issued before current MFMAs; bridges m->h loops).
// GRU register-local (h_prev from R1). Phase 3 (!last): s = lrelu(h@WS+bS).
// ---------------------------------------------------------------------------
__global__ __launch_bounds__(256) void layer_kernel(
    const bf16* __restrict__ cat,    // [N64][256] = [agg | h]
    const bf16* __restrict__ WM,     // [256][256] W_rec^T
    const float* __restrict__ bM,
    const bf16* __restrict__ WX,     // [512][384] W_ext^T (r|z|inn|hn)
    const float* __restrict__ bX,
    const bf16* __restrict__ WS,     // [128][128] W_snd^T
    const float* __restrict__ bS,
    bf16* __restrict__ catH,         // cat + 128 (ld 256)
    bf16* __restrict__ sbuf,         // [N64][128]; written iff !last
    float* __restrict__ out32,       // d_out (ld 128); written iff last
    int N, int last)
{
    __shared__ bf16 smem[24576];     // 48 KB
    bf16* R0 = smem;
    bf16* R1 = smem + 8192;
    bf16* R2 = smem + 16384;

    const int t  = threadIdx.x;
    const int wv = t >> 6, ln = t & 63, m16 = ln & 15, q = ln >> 4;
    const int row0 = blockIdx.x * 64;

    // ---- stage agg + h ----
#pragma unroll
    for (int i = 0; i < 8; ++i) {
        int s    = i * 256 + t;
        int R    = s >> 10;
        int row  = (s >> 4) & 63;
        int c    = (s & 15) ^ (row & 15);
        int grow = row0 + row; if (grow > N - 1) grow = N - 1;
        GLOAD_LDS16(cat + (size_t)grow * 256 + R * 128 + c * 8,
                    smem + ((i * 256 + wv * 64) << 3));
    }
    __syncthreads();

    // ---- phase 1: m = lrelu([agg|h] @ WM + bM); wave = 64 rows x 64 cols ----
    f32x4 macc[4][4];
#pragma unroll
    for (int mi = 0; mi < 4; ++mi)
#pragma unroll
        for (int ni = 0; ni < 4; ++ni)
            macc[mi][ni] = (f32x4){0.f, 0.f, 0.f, 0.f};

#pragma unroll
    for (int k0 = 0; k0 < 256; k0 += 32) {
        const bf16* Rg = (k0 < 128) ? R0 : R1;
        int kl = k0 & 127;
        short8 a[4], b[4];
#pragma unroll
        for (int ni = 0; ni < 4; ++ni)
            b[ni] = *reinterpret_cast<const short8*>(
                WM + (size_t)(wv * 64 + ni * 16 + m16) * 256 + k0 + q * 8);
#pragma unroll
        for (int mi = 0; mi < 4; ++mi) {
            int row = mi * 16 + m16;
            int c   = ((kl >> 3) + q) ^ m16;
            a[mi] = *reinterpret_cast<const short8*>(Rg + row * 128 + c * 8);
        }
#pragma unroll
        for (int mi = 0; mi < 4; ++mi)
#pragma unroll
            for (int ni = 0; ni < 4; ++ni)
                macc[mi][ni] = MFMA16(a[mi], b[ni], macc[mi][ni]);
    }
    __syncthreads();

    // ---- write m into R0 (ch<128) / R2 (ch>=128) ----
#pragma unroll
    for (int mi = 0; mi < 4; ++mi) {
#pragma unroll
        for (int ni = 0; ni < 4; ++ni) {
            int ch  = wv * 64 + ni * 16 + m16;
            bf16* MR = (ch < 128) ? R0 : R2;
            int chl = ch & 127;
            float bv = bM[ch];
#pragma unroll
            for (int r = 0; r < 4; ++r) {
                int row = mi * 16 + q * 4 + r;
                float v = macc[mi][ni][r] + bv;
                v = (v > 0.f) ? v : LRELU_SLOPE * v;
                short sv = f2b(v);
                MR[row * 128 + (((chl >> 3) ^ (row & 15)) << 3) + (chl & 7)] =
                    *reinterpret_cast<bf16*>(&sv);
            }
        }
    }
    __syncthreads();

    // ---- phase 2: gates; wave = 64 rows x 32 ch x 4 gates; pipelined ----
    f32x4 gr[4][2], gz[4][2], gn_[4][2], gh_[4][2];
#pragma unroll
    for (int mi = 0; mi < 4; ++mi)
#pragma unroll
        for (int ni = 0; ni < 2; ++ni) {
            gr[mi][ni]  = (f32x4){0.f, 0.f, 0.f, 0.f};
            gz[mi][ni]  = (f32x4){0.f, 0.f, 0.f, 0.f};
            gn_[mi][ni] = (f32x4){0.f, 0.f, 0.f, 0.f};
            gh_[mi][ni] = (f32x4){0.f, 0.f, 0.f, 0.f};
        }

    short8 brC[2], bzC[2], bxC[2];
#pragma unroll
    for (int ni = 0; ni < 2; ++ni) {
        int cw = wv * 32 + ni * 16 + m16;
        brC[ni] = *reinterpret_cast<const short8*>(WX + (size_t)(cw)       * 384 + q * 8);
        bzC[ni] = *reinterpret_cast<const short8*>(WX + (size_t)(128 + cw) * 384 + q * 8);
        bxC[ni] = *reinterpret_cast<const short8*>(WX + (size_t)(256 + cw) * 384 + q * 8);
    }

    // k in [0,256): A = m (R0/R2); gates r, z, inn (bx = inn plane)
#pragma unroll
    for (int k0 = 0; k0 < 256; k0 += 32) {
        const int kn = k0 + 32;
        short8 brN[2], bzN[2], bxN[2];
#pragma unroll
        for (int ni = 0; ni < 2; ++ni) {
            int cw = wv * 32 + ni * 16 + m16;
            if (kn < 256) {
                brN[ni] = *reinterpret_cast<const short8*>(WX + (size_t)(cw)       * 384 + kn + q * 8);
                bzN[ni] = *reinterpret_cast<const short8*>(WX + (size_t)(128 + cw) * 384 + kn + q * 8);
                bxN[ni] = *reinterpret_cast<const short8*>(WX + (size_t)(256 + cw) * 384 + kn + q * 8);
            } else {   // bridge into h-loop: bx switches to hn plane
                brN[ni] = *reinterpret_cast<const short8*>(WX + (size_t)(cw)       * 384 + 256 + q * 8);
                bzN[ni] = *reinterpret_cast<const short8*>(WX + (size_t)(128 + cw) * 384 + 256 + q * 8);
                bxN[ni] = *reinterpret_cast<const short8*>(WX + (size_t)(384 + cw) * 384 + 256 + q * 8);
            }
        }
        const bf16* Rg = (k0 < 128) ? R0 : R2;
        int kl = k0 & 127;
        short8 a[4];
#pragma unroll
        for (int mi = 0; mi < 4; ++mi) {
            int row = mi * 16 + m16;
            int c   = ((kl >> 3) + q) ^ m16;
            a[mi] = *reinterpret_cast<const short8*>(Rg + row * 128 + c * 8);
        }
#pragma unroll
        for (int mi = 0; mi < 4; ++mi)
#pragma unroll
            for (int ni = 0; ni < 2; ++ni) {
                gr[mi][ni]  = MFMA16(a[mi], brC[ni], gr[mi][ni]);
                gz[mi][ni]  = MFMA16(a[mi], bzC[ni], gz[mi][ni]);
                gn_[mi][ni] = MFMA16(a[mi], bxC[ni], gn_[mi][ni]);
            }
#pragma unroll
        for (int ni = 0; ni < 2; ++ni) {
            brC[ni] = brN[ni]; bzC[ni] = bzN[ni]; bxC[ni] = bxN[ni];
        }
    }
    // k in [256,384): A = h (R1); gates r, z, hn (bx = hn plane)
#pragma unroll
    for (int k0 = 256; k0 < 384; k0 += 32) {
        const int kn = k0 + 32;
        short8 brN[2], bzN[2], bxN[2];
#pragma unroll
        for (int ni = 0; ni < 2; ++ni) {
            if (kn < 384) {
                int cw = wv * 32 + ni * 16 + m16;
                brN[ni] = *reinterpret_cast<const short8*>(WX + (size_t)(cw)       * 384 + kn + q * 8);
                bzN[ni] = *reinterpret_cast<const short8*>(WX + (size_t)(128 + cw) * 384 + kn + q * 8);
                bxN[ni] = *reinterpret_cast<const short8*>(WX + (size_t)(384 + cw) * 384 + kn + q * 8);
            } else {
                brN[ni] = brC[ni]; bzN[ni] = bzC[ni]; bxN[ni] = bxC[ni];
            }
        }
        int kl = k0 - 256;
        short8 a[4];
#pragma unroll
        for (int mi = 0; mi < 4; ++mi) {
            int row = mi * 16 + m16;
            int c   = ((kl >> 3) + q) ^ m16;
            a[mi] = *reinterpret_cast<const short8*>(R1 + row * 128 + c * 8);
        }
#pragma unroll
        for (int mi = 0; mi < 4; ++mi)
#pragma unroll
            for (int ni = 0; ni < 2; ++ni) {
                gr[mi][ni]  = MFMA16(a[mi], brC[ni], gr[mi][ni]);
                gz[mi][ni]  = MFMA16(a[mi], bzC[ni], gz[mi][ni]);
                gh_[mi][ni] = MFMA16(a[mi], bxC[ni], gh_[mi][ni]);
            }
#pragma unroll
        for (int ni = 0; ni < 2; ++ni) {
            brC[ni] = brN[ni]; bzC[ni] = bzN[ni]; bxC[ni] = bxN[ni];
        }
    }
    __syncthreads();   // R0 (m_lo) reads done before h_out overwrites

    // ---- GRU: register-local; h_prev from R1; h_new -> R0 ----
#pragma unroll
    for (int mi = 0; mi < 4; ++mi) {
#pragma unroll
        for (int ni = 0; ni < 2; ++ni) {
            int ch = wv * 32 + ni * 16 + m16;
            float brv = bX[ch], bzv = bX[128 + ch];
            float bnv = bX[256 + ch], bhv = bX[384 + ch];
#pragma unroll
            for (int r = 0; r < 4; ++r) {
                int lrow = mi * 16 + q * 4 + r;
                int c = ((ch >> 3) ^ (lrow & 15)) << 3;
                float hv = b2f(*reinterpret_cast<const short*>(
                    R1 + lrow * 128 + c + (ch & 7)));
                float rr = 1.f / (1.f + __expf(-(gr[mi][ni][r] + brv)));
                float zz = 1.f / (1.f + __expf(-(gz[mi][ni][r] + bzv)));
                float nn = tanhf(gn_[mi][ni][r] + bnv + rr * (gh_[mi][ni][r] + bhv));
                float hnew = (1.f - zz) * nn + zz * hv;
                short hb = f2b(hnew);
                R0[lrow * 128 + c + (ch & 7)] = *reinterpret_cast<bf16*>(&hb);
            }
        }
    }
    __syncthreads();   // h_new complete; R1 reads complete

    // ---- copy-out h ----
#pragma unroll
    for (int i = 0; i < 4; ++i) {
        int s   = i * 256 + t;
        int row = s >> 4, c = s & 15;
        int grow = row0 + row;
        if (grow < N) {
            short8 v = *reinterpret_cast<const short8*>(
                R0 + row * 128 + ((c ^ (row & 15)) << 3));
            if (last) {
                f32x4 lo, hi;
#pragma unroll
                for (int j = 0; j < 4; ++j) { lo[j] = b2f(v[j]); hi[j] = b2f(v[j + 4]); }
                float* dst = out32 + (size_t)grow * 128 + c * 8;
                *reinterpret_cast<f32x4*>(dst)     = lo;
                *reinterpret_cast<f32x4*>(dst + 4) = hi;
            } else {
                *reinterpret_cast<short8*>(catH + (size_t)grow * 256 + c * 8) = v;
            }
        }
    }

    // ---- phase 3 (!last): s = lrelu(h_new @ WS + bS); wave = 64r x 32c ----
    if (!last) {
        f32x4 sacc[4][2];
#pragma unroll
        for (int mi = 0; mi < 4; ++mi)
#pragma unroll
            for (int ni = 0; ni < 2; ++ni)
                sacc[mi][ni] = (f32x4){0.f, 0.f, 0.f, 0.f};

#pragma unroll
        for (int k0 = 0; k0 < 128; k0 += 32) {
            short8 a[4], b[2];
#pragma unroll
            for (int ni = 0; ni < 2; ++ni)
                b[ni] = *reinterpret_cast<const short8*>(
                    WS + (size_t)(wv * 32 + ni * 16 + m16) * 128 + k0 + q * 8);
#pragma unroll
            for (int mi = 0; mi < 4; ++mi) {
                int row = mi * 16 + m16;
                int c   = ((k0 >> 3) + q) ^ m16;
                a[mi] = *reinterpret_cast<const short8*>(R0 + row * 128 + c * 8);
            }
#pragma unroll
            for (int mi = 0; mi < 4; ++mi)
#pragma unroll
                for (int ni = 0; ni < 2; ++ni)
                    sacc[mi][ni] = MFMA16(a[mi], b[ni], sacc[mi][ni]);
        }

        // s -> R1 (dead), then copy-out
#pragma unroll
        for (int mi = 0; mi < 4; ++mi) {
#pragma unroll
            for (int ni = 0; ni < 2; ++ni) {
                int ch = wv * 32 + ni * 16 + m16;
                float bv = bS[ch];
#pragma unroll
                for (int r = 0; r < 4; ++r) {
                    int row = mi * 16 + q * 4 + r;
                    float v = sacc[mi][ni][r] + bv;
                    v = (v > 0.f) ? v : LRELU_SLOPE * v;
                    short sv = f2b(v);
                    R1[row * 128 + (((ch >> 3) ^ (row & 15)) << 3) + (ch & 7)] =
                        *reinterpret_cast<bf16*>(&sv);
                }
            }
        }
        __syncthreads();
#pragma unroll
        for (int i = 0; i < 4; ++i) {
            int s   = i * 256 + t;
            int row = s >> 4, c = s & 15;
            int grow = row0 + row;
            if (grow < N) {
                short8 v = *reinterpret_cast<const short8*>(
                    R1 + row * 128 + ((c ^ (row & 15)) << 3));
                *reinterpret_cast<short8*>(sbuf + (size_t)grow * 128 + c * 8) = v;
            }
        }
    }
}

// ---------------------------------------------------------------------------
// prep: x->bf16, weight transposes, W_ext (512x384, zero-padded), b_ext
// ---------------------------------------------------------------------------
__global__ void prep_kernel(const float* __restrict__ x, bf16* __restrict__ xb, int nx,
                            const float* __restrict__ W_embed, bf16* __restrict__ TE,
                            const float* __restrict__ W_snd,   bf16* __restrict__ TS,
                            const float* __restrict__ W_rec,   bf16* __restrict__ TM,
                            const float* __restrict__ W_ih, const float* __restrict__ W_hh,
                            bf16* __restrict__ TX,
                            const float* __restrict__ b_ih, const float* __restrict__ b_hh,
                            float* __restrict__ bext)
{
    int t = blockIdx.x * 256 + threadIdx.x;
    if (t < nx) { xb[t] = __float2bfloat16(x[t]); return; }
    t -= nx;
    if (t < 8192)  { TE[(t % 128) * 64  + t / 128] = __float2bfloat16(W_embed[t]); return; }
    t -= 8192;
    if (t < 16384) { TS[(t % 128) * 128 + t / 128] = __float2bfloat16(W_snd[t]); return; }
    t -= 16384;
    if (t < 65536) { TM[(t % 256) * 256 + t / 256] = __float2bfloat16(W_rec[t]); return; }
    t -= 65536;
    if (t < 196608) {
        int c = t / 384, k = t - c * 384;
        float v;
        if (c < 256)      v = (k < 256) ? W_ih[k * 384 + c] : W_hh[(k - 256) * 384 + c];
        else if (c < 384) v = (k < 256) ? W_ih[k * 384 + c] : 0.f;
        else              v = (k < 256) ? 0.f : W_hh[(k - 256) * 384 + (c - 128)];
        TX[t] = __float2bfloat16(v);
        return;
    }
    t -= 196608;
    if (t < 512) {
        float v;
        if (t < 256)      v = b_ih[t] + b_hh[t];
        else if (t < 384) v = b_ih[t];
        else              v = b_hh[t - 128];
        bext[t] = v;
    }
}

// ---------------------------------------------------------------------------
// CSR build
// ---------------------------------------------------------------------------
__global__ void hist_kernel(const int* __restrict__ col, int* __restrict__ cnt, int E)
{
    int e = blockIdx.x * 256 + threadIdx.x;
    if (e < E) atomicAdd(&cnt[col[e]], 1);
}

__global__ void blockscan_kernel(const int* __restrict__ cnt, int* __restrict__ off,
                                 int* __restrict__ bsum, int N)
{
    __shared__ int sm[256];
    int i = blockIdx.x * 256 + threadIdx.x;
    int v = (i < N) ? cnt[i] : 0;
    sm[threadIdx.x] = v;
    __syncthreads();
    for (int d = 1; d < 256; d <<= 1) {
        int tv = (threadIdx.x >= (unsigned)d) ? sm[threadIdx.x - d] : 0;
        __syncthreads();
        sm[threadIdx.x] += tv;
        __syncthreads();
    }
    if (i < N) off[i] = sm[threadIdx.x] - v;
    if (threadIdx.x == 255) bsum[blockIdx.x] = sm[255];
}

__global__ void bscan_kernel(int* __restrict__ bsum, int nb)
{
    __shared__ int sm[512];
    int v = (threadIdx.x < (unsigned)nb) ? bsum[threadIdx.x] : 0;
    sm[threadIdx.x] = v;
    __syncthreads();
    for (int d = 1; d < 512; d <<= 1) {
        int tv = (threadIdx.x >= (unsigned)d) ? sm[threadIdx.x - d] : 0;
        __syncthreads();
        sm[threadIdx.x] += tv;
        __syncthreads();
    }
    if (threadIdx.x < (unsigned)nb) bsum[threadIdx.x] = sm[threadIdx.x] - v;
}

__global__ void addoff_kernel(int* __restrict__ off, const int* __restrict__ bsum,
                              const int* __restrict__ cnt, float* __restrict__ icnt,
                              int N, int E)
{
    int i = blockIdx.x * 256 + threadIdx.x;
    if (i < N) {
        off[i] += bsum[blockIdx.x];
        icnt[i] = 1.0f / fmaxf((float)cnt[i], 1.0f);
    }
    if (i == 0) off[N] = E;
}

// packed (row, weight) 8B scatter
__global__ void fill_kernel(const int* __restrict__ row, const int* __restrict__ col,
                            const float* __restrict__ ea, const int* __restrict__ off,
                            int* __restrict__ fil, int2* __restrict__ re, int E)
{
    int e = blockIdx.x * 256 + threadIdx.x;
    if (e < E) {
        int c = col[e];
        int p = atomicAdd(&fil[c], 1);
        int2 v; v.x = row[e]; v.y = __float_as_int(ea[e]);
        re[off[c] + p] = v;
    }
}

// ---------------------------------------------------------------------------
// aggregation: wave per node; 4x16-lane groups, one edge per group per trip,
// unrolled x2 (8 gathers in flight per wave)
// ---------------------------------------------------------------------------
__global__ void agg_kernel(const int* __restrict__ off,
                           const int2* __restrict__ re,
                           const bf16* __restrict__ s,
                           const float* __restrict__ icnt,
                           bf16* __restrict__ cat, int N)
{
    int wid  = (int)((blockIdx.x * blockDim.x + threadIdx.x) >> 6);
    int lane = threadIdx.x & 63;
    if (wid >= N) return;
    const int rg = lane >> 4;
    const int cl = lane & 15;
    int b = off[wid], e = off[wid + 1];

    float acc[8];
#pragma unroll
    for (int j = 0; j < 8; ++j) acc[j] = 0.f;

    int i = b + rg;
    for (; i + 4 < e; i += 8) {
        int2 p0 = re[i];
        int2 p1 = re[i + 4];
        short8 v0 = *reinterpret_cast<const short8*>(s + (size_t)p0.x * 128 + cl * 8);
        short8 v1 = *reinterpret_cast<const short8*>(s + (size_t)p1.x * 128 + cl * 8);
        float w0 = __int_as_float(p0.y), w1 = __int_as_float(p1.y);
#pragma unroll
        for (int j = 0; j < 8; ++j) acc[j] += w0 * b2f(v0[j]) + w1 * b2f(v1[j]);
    }
    if (i < e) {
        int2 p0 = re[i];
        float w0 = __int_as_float(p0.y);
        short8 v0 = *reinterpret_cast<const short8*>(s + (size_t)p0.x * 128 + cl * 8);
#pragma unroll
        for (int j = 0; j < 8; ++j) acc[j] += w0 * b2f(v0[j]);
    }
#pragma unroll
    for (int j = 0; j < 8; ++j) {
        acc[j] += __shfl_xor(acc[j], 16, 64);
        acc[j] += __shfl_xor(acc[j], 32, 64);
    }
    if (rg == 0) {
        float ic = icnt[wid];
        short8 o;
#pragma unroll
        for (int j = 0; j < 8; ++j) o[j] = f2b(acc[j] * ic);
        *reinterpret_cast<short8*>(cat + (size_t)wid * 256 + cl * 8) = o;
    }
}

// ---------------------------------------------------------------------------
extern "C" void kernel_launch(void* const* d_in, const int* in_sizes, int n_in,
                              void* d_out, int out_size, void* d_ws, size_t ws_size,
                              hipStream_t stream)
{
    const float* x       = (const float*)d_in[0];
    const int*   ei      = (const int*)d_in[1];
    const float* ea      = (const float*)d_in[2];
    const float* W_embed = (const float*)d_in[4];
    const float* b_embed = (const float*)d_in[5];
    const float* W_snd   = (const float*)d_in[6];
    const float* b_snd   = (const float*)d_in[7];
    const float* W_rec   = (const float*)d_in[8];
    const float* b_rec   = (const float*)d_in[9];
    const float* W_ih    = (const float*)d_in[10];
    const float* b_ih    = (const float*)d_in[11];
    const float* W_hh    = (const float*)d_in[12];
    const float* b_hh    = (const float*)d_in[13];

    const int N = in_sizes[3];
    const int E = in_sizes[2];
    const int N64 = ((N + 63) / 64) * 64;

    char* p = (char*)d_ws;
    auto carve = [&](size_t bytes) {
        char* r = p;
        p += (bytes + 255) & ~(size_t)255;
        return (void*)r;
    };
    bf16*  xb   = (bf16*) carve((size_t)N64 * 64  * 2);
    bf16*  cat  = (bf16*) carve((size_t)N64 * 256 * 2);   // [agg | h]
    bf16*  sbuf = (bf16*) carve((size_t)N64 * 128 * 2);
    int2*  re   = (int2*) carve((size_t)E * 8);
    int*   cnt  = (int*)  carve((size_t)N * 4);
    int*   fil  = (int*)  carve((size_t)N * 4);
    int*   off  = (int*)  carve((size_t)(N + 1) * 4);
    int*   bsum = (int*)  carve((size_t)512 * 4);
    float* icnt = (float*)carve((size_t)N * 4);
    bf16*  wtE  = (bf16*) carve((size_t)128 * 64 * 2);
    bf16*  wtS  = (bf16*) carve((size_t)128 * 128 * 2);
    bf16*  wtM  = (bf16*) carve((size_t)256 * 256 * 2);
    bf16*  wtX  = (bf16*) carve((size_t)512 * 384 * 2);
    float* bext = (float*)carve((size_t)512 * 4);

    const int* rowp = ei;
    const int* colp = ei + E;

    hipMemsetAsync(cnt, 0, (size_t)N * 4, stream);
    hipMemsetAsync(fil, 0, (size_t)N * 4, stream);

    const int TB = 256;
    auto nb = [](int n) { return (n + 255) / 256; };

    prep_kernel<<<nb(N * 64 + 287232), TB, 0, stream>>>(
        x, xb, N * 64, W_embed, wtE, W_snd, wtS, W_rec, wtM,
        W_ih, W_hh, wtX, b_ih, b_hh, bext);

    hist_kernel<<<nb(E), TB, 0, stream>>>(colp, cnt, E);
    blockscan_kernel<<<nb(N), TB, 0, stream>>>(cnt, off, bsum, N);
    bscan_kernel<<<1, 512, 0, stream>>>(bsum, nb(N));
    addoff_kernel<<<nb(N), TB, 0, stream>>>(off, bsum, cnt, icnt, N, E);
    fill_kernel<<<nb(E), TB, 0, stream>>>(rowp, colp, ea, off, fil, re, E);

    const int gx = (N + 63) / 64;

    // embed: h = x @ W_embed + b -> cat[:,128:]; s0 = lrelu(h@Ws+bs) -> sbuf
    embed_kernel<<<gx, TB, 0, stream>>>(xb, wtE, b_embed, wtS, b_snd,
                                        cat + 128, sbuf, N);

    for (int L = 0; L < 3; ++L) {
        // agg = segment_mean(s[row] * ea) -> cat[:,0:128]
        agg_kernel<<<(N * 64 + TB - 1) / TB, TB, 0, stream>>>(off, re, sbuf,
                                                              icnt, cat, N);
        // fused m + gates + GRU (+ next-layer s) -> cat h / sbuf / d_out
        layer_kernel<<<gx, TB, 0, stream>>>(cat, wtM, b_rec, wtX, bext,
                                            wtS, b_snd,
                                            cat + 128, sbuf, (float*)d_out,
                                            N, (L == 2) ? 1 : 0);
    }
}